// Round 3
// baseline (66.606 us; speedup 1.0000x reference)
//
#include <hip/hip_runtime.h>

// PackedStdScaler: grouped (sample_id, variate_id) masked mean/std over (B,S,D)
// B=4, S=2048, D=128; ids in [0,8) -> 64 groups/batch.
// One block per (b, group): gather row list (ballot compaction, 1 LDS atomic
// per wave), 4-deep batched row loop (single latency exposure), write loc/scale.

#define BB 4
#define SS 2048
#define DD 128
#define NG 64
#define NT 512          // 8 waves/block
#define NW (NT / 64)

__global__ __launch_bounds__(NT) void pss_kernel(
    const float* __restrict__ target,
    const unsigned* __restrict__ mask_raw,   // raw words of observed_mask buffer
    const int* __restrict__ sample_id,
    const int* __restrict__ variate_id,
    float* __restrict__ out)                 // [0,B*S): loc, [B*S,2*B*S): scale
{
    const int b    = blockIdx.y;
    const int g    = blockIdx.x;
    const int tid  = threadIdx.x;
    const int lane = tid & 63;
    const int wave = tid >> 6;

    __shared__ unsigned short rows[SS];
    __shared__ int nrows;
    __shared__ int mflag;
    __shared__ double red[NW][3];
    __shared__ float bcast[2];

    if (tid == 0) { nrows = 0; mflag = 0; }
    __syncthreads();

    // --- mask dtype detection: byte-bool buffer => some of first 64 words > 1
    if (mask_raw[tid & 63] > 1u) atomicOr(&mflag, 1);

    // --- gather rows of group g (batch b): int4 id loads (one iteration:
    // NT*4 == SS), ballot compaction with ONE LDS atomic per wave.
    {
        const int4 sv = ((const int4*)(sample_id + b * SS))[tid];
        const int4 vv = ((const int4*)(variate_id + b * SS))[tid];
        const int keys[4] = { sv.x * 8 + vv.x, sv.y * 8 + vv.y,
                              sv.z * 8 + vv.z, sv.w * 8 + vv.w };
        unsigned long long bal[4];
        #pragma unroll
        for (int j = 0; j < 4; j++) bal[j] = __ballot(keys[j] == g);

        const int tot = __popcll(bal[0]) + __popcll(bal[1]) +
                        __popcll(bal[2]) + __popcll(bal[3]);
        int base = 0;
        if (tot) {
            if (lane == 0) base = atomicAdd(&nrows, tot);
            base = __shfl(base, 0, 64);
            const unsigned long long below = (1ull << lane) - 1ull;
            int off = 0;
            #pragma unroll
            for (int j = 0; j < 4; j++) {
                if (keys[j] == g) {
                    const int pre = __popcll(bal[j] & below);
                    rows[base + off + pre] = (unsigned short)(4 * tid + j);
                }
                off += __popcll(bal[j]);
            }
        }
    }
    __syncthreads();
    const bool bytemask = (mflag != 0);
    const int M = nrows;

    // --- accumulate cnt / sum / sumsq. One wave per row, 64 lanes x float2 =
    // full row. 4-deep batch: one ds_read_b64 for indices, all global loads
    // issued before any use -> single latency exposure per round.
    float  c  = 0.f;
    double s1 = 0.0, s2 = 0.0;
    for (int base = wave * 4; base < M; base += NW * 4) {
        const int n = M - base;                          // >0
        const ushort4 r4 = *(const ushort4*)&rows[base]; // 8B-aligned (base%4==0)
        const int sidx[4] = { r4.x, r4.y, r4.z, r4.w };
        float2 tv[4];
        int    m0[4], m1[4];
        #pragma unroll
        for (int j = 0; j < 4; j++) {
            if (j < n) {
                const size_t rowoff = ((size_t)(b * SS + sidx[j])) * DD;
                tv[j] = ((const float2*)(target + rowoff))[lane];
                if (bytemask) {
                    const uchar2 mv =
                        ((const uchar2*)(((const unsigned char*)mask_raw) + rowoff))[lane];
                    m0[j] = mv.x; m1[j] = mv.y;
                } else {
                    const int2 mv =
                        ((const int2*)(((const int*)mask_raw) + rowoff))[lane];
                    m0[j] = mv.x; m1[j] = mv.y;
                }
            }
        }
        #pragma unroll
        for (int j = 0; j < 4; j++) {
            if (j < n) {
                if (m0[j]) { c += 1.f; s1 += (double)tv[j].x;
                             s2 += (double)tv[j].x * (double)tv[j].x; }
                if (m1[j]) { c += 1.f; s1 += (double)tv[j].y;
                             s2 += (double)tv[j].y * (double)tv[j].y; }
            }
        }
    }

    // --- wave reduce (64 lanes), then cross-wave via LDS
    for (int off = 32; off > 0; off >>= 1) {
        c  += __shfl_down(c,  off, 64);
        s1 += __shfl_down(s1, off, 64);
        s2 += __shfl_down(s2, off, 64);
    }
    if (lane == 0) { red[wave][0] = (double)c; red[wave][1] = s1; red[wave][2] = s2; }
    __syncthreads();

    if (tid == 0) {
        double cnt = 0, gs = 0, gss = 0;
        for (int w = 0; w < NW; w++) {
            cnt += red[w][0]; gs += red[w][1]; gss += red[w][2];
        }
        // safe_div semantics: den==0 -> divide by 1
        const double loc = gs / (cnt == 0.0 ? 1.0 : cnt);
        double varnum = gss - 2.0 * loc * gs + loc * loc * cnt; // == sum((t-loc)^2*obs)
        if (varnum < 0.0) varnum = 0.0;                          // fp cancellation guard
        const double den = cnt - 1.0;                            // CORRECTION = 1
        const double var = varnum / (den == 0.0 ? 1.0 : den);
        float locf   = (float)loc;
        float scalef = (float)sqrt(var + 1e-5);                  // MINIMUM_SCALE
        if (g < 8) { locf = 0.f; scalef = 1.f; }                 // sample_id==0 padding
        bcast[0] = locf; bcast[1] = scalef;
    }
    __syncthreads();

    const float locf = bcast[0], scalef = bcast[1];
    for (int i = tid; i < M; i += NT) {
        const int s = rows[i];
        out[b * SS + s]           = locf;
        out[BB * SS + b * SS + s] = scalef;
    }
}

extern "C" void kernel_launch(void* const* d_in, const int* in_sizes, int n_in,
                              void* d_out, int out_size, void* d_ws, size_t ws_size,
                              hipStream_t stream) {
    const float*    target = (const float*)d_in[0];
    const unsigned* mask   = (const unsigned*)d_in[1];
    const int*      sid    = (const int*)d_in[2];
    const int*      vid    = (const int*)d_in[3];
    float*          out    = (float*)d_out;

    dim3 grid(NG, BB);
    hipLaunchKernelGGL(pss_kernel, grid, dim3(NT), 0, stream,
                       target, mask, sid, vid, out);
}